// Round 2
// baseline (517.371 us; speedup 1.0000x reference)
//
#include <hip/hip_runtime.h>
#include <math.h>
#include <float.h>

#define L_   4096
#define M_   8192
#define H_   8
#define D_   64
#define KK   45          // 5 * ceil(ln(4096))
#define NTHR 512

// ws layout in float2 units
#define WS_C   0         // c[4096]  : e^{-i pi j^2 / 8191}
#define WS_D   4096      // d[4096]  : e^{+i pi j^2 / 8190}
#define WS_TW  8192      // tw[4096] : e^{-2 pi i j / 8192}
#define WS_H1  12288     // H1s[8192]: DIF-FFT(conj-chirp c), pre-scaled 1/8192, bit-reversed
#define WS_H2  20480     // H2s[8192]: same for d
// total 28672 float2 = 229376 bytes

__device__ __forceinline__ float2 cmulf(float2 a, float2 b) {
  return make_float2(a.x * b.x - a.y * b.y, a.x * b.y + a.y * b.x);
}
__device__ __forceinline__ float2 cmulcf(float2 a, float2 b) {  // a * conj(b)
  return make_float2(a.x * b.x + a.y * b.y, a.y * b.x - a.x * b.y);
}

// DIF radix-2: natural in -> bit-reversed out, twiddle e^{-2pi i/M}.
static __device__ void fft_dif(float2* buf, const float2* __restrict__ tw) {
  const int tid = threadIdx.x;
  for (int st = 0; st < 13; ++st) {
    const int h = 4096 >> st;
    __syncthreads();
    #pragma unroll
    for (int r = 0; r < 8; ++r) {
      const int b  = tid + (r << 9);
      const int j  = b & (h - 1);
      const int g  = b >> (12 - st);
      const int i0 = (g << (13 - st)) + j;
      const int i1 = i0 + h;
      const float2 u = buf[i0];
      const float2 v = buf[i1];
      const float2 s = make_float2(u.x + v.x, u.y + v.y);
      const float2 t = make_float2(u.x - v.x, u.y - v.y);
      const float2 w = tw[j << st];
      buf[i0] = s;
      buf[i1] = make_float2(t.x * w.x - t.y * w.y, t.x * w.y + t.y * w.x);
    }
  }
  __syncthreads();
}

// DIT radix-2 inverse: bit-reversed in -> natural out, twiddle e^{+2pi i/M}.
// Composition fft_dit_inv(fft_dif(x)) = 8192 * x (scale folded into H1s/H2s).
static __device__ void fft_dit_inv(float2* buf, const float2* __restrict__ tw) {
  const int tid = threadIdx.x;
  for (int st = 12; st >= 0; --st) {
    const int h = 4096 >> st;
    __syncthreads();
    #pragma unroll
    for (int r = 0; r < 8; ++r) {
      const int b  = tid + (r << 9);
      const int j  = b & (h - 1);
      const int g  = b >> (12 - st);
      const int i0 = (g << (13 - st)) + j;
      const int i1 = i0 + h;
      const float2 w = tw[j << st];
      const float2 v = buf[i1];
      const float2 t = make_float2(v.x * w.x + v.y * w.y, v.y * w.x - v.x * w.y); // v*conj(w)
      const float2 u = buf[i0];
      buf[i0] = make_float2(u.x + t.x, u.y + t.y);
      buf[i1] = make_float2(u.x - t.x, u.y - t.y);
    }
  }
  __syncthreads();
}

extern "C" __global__ void setup_tables(float2* ws) {
  const int idx = blockIdx.x * 512 + threadIdx.x;
  if (idx < 4096) {
    const long p = ((long)idx * idx) % 16382;      // j^2 mod 2*8191
    const double th = -M_PI * (double)p / 8191.0;
    double s, c; sincos(th, &s, &c);
    ws[WS_C + idx] = make_float2((float)c, (float)s);
  } else if (idx < 8192) {
    const int j = idx - 4096;
    const long p = ((long)j * j) % 16380;          // j^2 mod 2*8190
    const double th = M_PI * (double)p / 8190.0;
    double s, c; sincos(th, &s, &c);
    ws[WS_D + j] = make_float2((float)c, (float)s);
  } else if (idx < 12288) {
    const int j = idx - 8192;
    const double th = -M_PI * (double)j / 4096.0;  // e^{-2pi i j/8192}
    double s, c; sincos(th, &s, &c);
    ws[WS_TW + j] = make_float2((float)c, (float)s);
  }
}

extern "C" __global__ __launch_bounds__(512, 1) void setup_filters(float2* ws) {
  __shared__ float2 buf[M_];
  const float2* src = ws + (blockIdx.x == 0 ? WS_C : WS_D);
  float2*       dst = ws + (blockIdx.x == 0 ? WS_H1 : WS_H2);
  const float2* tw  = ws + WS_TW;
  for (int i = threadIdx.x; i < M_; i += 512) {
    float2 val = make_float2(0.f, 0.f);
    if (i != 4096) {                       // kernel support |j| <= 4095
      const int jj = (i <= 4095) ? i : (M_ - i);   // chirp is even in j
      const float2 e = src[jj];
      val = make_float2(e.x, -e.y);        // conj(chirp)
    }
    buf[i] = val;
  }
  fft_dif(buf, tw);
  const float sc = 1.0f / 8192.0f;         // fold IFFT scaling into the filter
  for (int i = threadIdx.x; i < M_; i += 512)
    dst[i] = make_float2(buf[i].x * sc, buf[i].y * sc);
}

extern "C" __global__ __launch_bounds__(NTHR, 1)
void autocorr_main(const float* __restrict__ queries, const float* __restrict__ keys,
                   const float* __restrict__ values,
                   const float* __restrict__ Wq, const float* __restrict__ bq,
                   const float* __restrict__ Wk, const float* __restrict__ bk,
                   const float* __restrict__ Wv, const float* __restrict__ bv,
                   const float2* __restrict__ ws, float* __restrict__ outp)
{
  __shared__ float2 buf[M_];        // 64 KB FFT buffer
  __shared__ float2 spec[L_];       // 32 KB: K-spec, then F = Q*conj(K)
  __shared__ float  qk[M_];         // 32 KB: q[0..4096), k[4096..8192)
  __shared__ float  vv_lds[L_];     // 16 KB
  __shared__ float  cand_v[8 * KK];
  __shared__ int    cand_i[8 * KK];
  __shared__ float  w_sh[KK];
  __shared__ int    i_sh[KK];

  const int tid = threadIdx.x;
  const int bh  = blockIdx.x;
  const int b   = bh >> 3;
  const int h   = bh & 7;
  const int lane16 = tid & 15;
  const int grp    = tid >> 4;      // 0..31

  const float2* c_t = ws + WS_C;
  const float2* d_t = ws + WS_D;
  const float2* tw  = ws + WS_TW;
  const float2* H1  = ws + WS_H1;
  const float2* H2  = ws + WS_H2;

  // ---------------- Phase A: projections (q,k in fp64 accumulation) ----------------
  {
    const float* srcs[3] = {queries, keys, values};
    const float* Wsx[3]  = {Wq, Wk, Wv};
    const float* Bsx[3]  = {bq, bk, bv};
    #pragma unroll
    for (int s = 0; s < 3; ++s) {
      const float* base = srcs[s] + ((size_t)b * (L_ * H_) + h) * (size_t)D_;
      const float4 w4 = reinterpret_cast<const float4*>(Wsx[s])[lane16];
      const float bias = Bsx[s][0];
      #pragma unroll 2
      for (int p = 0; p < L_ / 32; ++p) {
        const int l = p * 32 + grp;
        const float4 x = reinterpret_cast<const float4*>(base + (size_t)l * (H_ * D_))[lane16];
        if (s < 2) {
          double dot = (double)x.x * w4.x + (double)x.y * w4.y +
                       (double)x.z * w4.z + (double)x.w * w4.w;
          dot += __shfl_xor(dot, 1);
          dot += __shfl_xor(dot, 2);
          dot += __shfl_xor(dot, 4);
          dot += __shfl_xor(dot, 8);
          if (lane16 == 0) qk[s * L_ + l] = (float)(dot + (double)bias);
        } else {
          float dot = x.x * w4.x + x.y * w4.y + x.z * w4.z + x.w * w4.w;
          dot += __shfl_xor(dot, 1);
          dot += __shfl_xor(dot, 2);
          dot += __shfl_xor(dot, 4);
          dot += __shfl_xor(dot, 8);
          if (lane16 == 0) vv_lds[l] = dot + bias;
        }
      }
    }
  }
  __syncthreads();

  // ---------------- Phase B: Bluestein forward CZT (8191-grid) for K then Q --------
  // K_m = c_m * IFFT(FFT(k*c) . H1)[m]
  for (int i = tid; i < M_; i += NTHR) {
    float2 x = make_float2(0.f, 0.f);
    if (i < L_) { const float kv = qk[L_ + i]; const float2 cc = c_t[i];
                  x = make_float2(kv * cc.x, kv * cc.y); }
    buf[i] = x;
  }
  fft_dif(buf, tw);
  for (int i = tid; i < M_; i += NTHR) buf[i] = cmulf(buf[i], H1[i]);
  fft_dit_inv(buf, tw);
  for (int m = tid; m < L_; m += NTHR) spec[m] = cmulf(c_t[m], buf[m]);
  __syncthreads();

  // Q, then F = Q * conj(K)
  for (int i = tid; i < M_; i += NTHR) {
    float2 x = make_float2(0.f, 0.f);
    if (i < L_) { const float qv = qk[i]; const float2 cc = c_t[i];
                  x = make_float2(qv * cc.x, qv * cc.y); }
    buf[i] = x;
  }
  fft_dif(buf, tw);
  for (int i = tid; i < M_; i += NTHR) buf[i] = cmulf(buf[i], H1[i]);
  fft_dit_inv(buf, tw);
  for (int m = tid; m < L_; m += NTHR) {
    const float2 Q = cmulf(c_t[m], buf[m]);
    spec[m] = cmulcf(Q, spec[m]);
  }
  __syncthreads();

  // ---------------- Phase C: inverse via irfft_8190 semantics (Bluestein CZT) ------
  // y_t = Re( d_t * IFFT(FFT(g.d) . H2)[t] ) / 8190, g = [ReF0, 2F_1..2F_4094, ReF_4095]
  for (int i = tid; i < M_; i += NTHR) {
    float2 x = make_float2(0.f, 0.f);
    if (i < L_) {
      const float2 F = spec[i];
      float2 g;
      if (i == 0 || i == 4095) g = make_float2(F.x, 0.f);  // DC/Nyquist: Im dropped
      else                     g = make_float2(2.f * F.x, 2.f * F.y);
      x = cmulf(g, d_t[i]);
    }
    buf[i] = x;
  }
  fft_dif(buf, tw);
  for (int i = tid; i < M_; i += NTHR) buf[i] = cmulf(buf[i], H2[i]);
  fft_dit_inv(buf, tw);

  // ---------------- scores + per-wave top-45 ----------------
  const float SCALE = (float)(1.0 / (8190.0 * 4096.0));   // /8190 (irfft) then /4096 (L)
  float svv[8]; int sii[8];
  #pragma unroll
  for (int i2 = 0; i2 < 8; ++i2) {
    const int t = tid * 8 + i2;
    const float2 Z = cmulf(d_t[t], buf[t]);
    svv[i2] = Z.x * SCALE;
    sii[i2] = t;
  }
  const int lane = tid & 63, wv = tid >> 6;   // 8 waves
  for (int it = 0; it < KK; ++it) {
    float bvv = -FLT_MAX; int bii = 0x7fffffff;
    #pragma unroll
    for (int c = 0; c < 8; ++c)
      if (svv[c] > bvv || (svv[c] == bvv && sii[c] < bii)) { bvv = svv[c]; bii = sii[c]; }
    #pragma unroll
    for (int off = 1; off < 64; off <<= 1) {
      const float ov = __shfl_xor(bvv, off);
      const int   oi = __shfl_xor(bii, off);
      if (ov > bvv || (ov == bvv && oi < bii)) { bvv = ov; bii = oi; }
    }
    #pragma unroll
    for (int c = 0; c < 8; ++c) if (sii[c] == bii) svv[c] = -FLT_MAX;
    if (lane == 0) { cand_v[wv * KK + it] = bvv; cand_i[wv * KK + it] = bii; }
  }
  __syncthreads();

  // ---------------- merge 8x45 + softmax (wave 0) ----------------
  if (tid < 64) {
    float mv[6]; int mi[6];
    #pragma unroll
    for (int c = 0; c < 6; ++c) {
      const int id = tid + 64 * c;
      if (id < 8 * KK) { mv[c] = cand_v[id]; mi[c] = cand_i[id]; }
      else             { mv[c] = -FLT_MAX;   mi[c] = 0x7fffffff; }
    }
    float m0 = 0.f, sum = 0.f, myv = -FLT_MAX; int myi = 0;
    for (int it = 0; it < KK; ++it) {
      float bvv = -FLT_MAX; int bii = 0x7fffffff;
      #pragma unroll
      for (int c = 0; c < 6; ++c)
        if (mv[c] > bvv || (mv[c] == bvv && mi[c] < bii)) { bvv = mv[c]; bii = mi[c]; }
      #pragma unroll
      for (int off = 1; off < 64; off <<= 1) {
        const float ov = __shfl_xor(bvv, off);
        const int   oi = __shfl_xor(bii, off);
        if (ov > bvv || (ov == bvv && oi < bii)) { bvv = ov; bii = oi; }
      }
      if (it == 0) m0 = bvv;
      sum += expf(bvv - m0);               // identical on all lanes
      if (tid == it) { myv = bvv; myi = bii; }
      #pragma unroll
      for (int c = 0; c < 6; ++c) if (mi[c] == bii) mv[c] = -FLT_MAX;
    }
    if (tid < KK) { w_sh[tid] = expf(myv - m0) / sum; i_sh[tid] = myi; }
  }
  __syncthreads();

  // ---------------- Phase D: out[t] = sum_j w_j * v[(idx_j + t) & 4095] ------------
  {
    float acc[8] = {0, 0, 0, 0, 0, 0, 0, 0};
    for (int j = 0; j < KK; ++j) {
      const float wj = w_sh[j];
      const int   bse = i_sh[j] + tid;
      #pragma unroll
      for (int i2 = 0; i2 < 8; ++i2)
        acc[i2] = fmaf(wj, vv_lds[(bse + (i2 << 9)) & (L_ - 1)], acc[i2]);
    }
    float* op = outp + (size_t)bh * L_;
    #pragma unroll
    for (int i2 = 0; i2 < 8; ++i2) op[tid + (i2 << 9)] = acc[i2];
  }
}

extern "C" void kernel_launch(void* const* d_in, const int* in_sizes, int n_in,
                              void* d_out, int out_size, void* d_ws, size_t ws_size,
                              hipStream_t stream) {
  const float* queries = (const float*)d_in[0];
  const float* keys    = (const float*)d_in[1];
  const float* values  = (const float*)d_in[2];
  const float* Wq = (const float*)d_in[3];
  const float* bq = (const float*)d_in[4];
  const float* Wk = (const float*)d_in[5];
  const float* bk = (const float*)d_in[6];
  const float* Wv = (const float*)d_in[7];
  const float* bv = (const float*)d_in[8];
  float2* ws = (float2*)d_ws;
  float* out = (float*)d_out;

  hipLaunchKernelGGL(setup_tables,  dim3(24), dim3(512), 0, stream, ws);
  hipLaunchKernelGGL(setup_filters, dim3(2),  dim3(512), 0, stream, ws);
  hipLaunchKernelGGL(autocorr_main, dim3(256), dim3(NTHR), 0, stream,
                     queries, keys, values, Wq, bq, Wk, bk, Wv, bv, ws, out);
}

// Round 3
// 396.506 us; speedup vs baseline: 1.3048x; 1.3048x over previous
//
#include <hip/hip_runtime.h>
#include <math.h>
#include <float.h>

#define L_   4096
#define M_   8192
#define H_   8
#define D_   64
#define KK   45          // 5 * ceil(ln(4096))

// ws layout in float2 units
#define WS_C   0         // c[4096]  : e^{-i pi j^2 / 8191}
#define WS_D   4096      // d[4096]  : e^{+i pi j^2 / 8190}
#define WS_TW  8192      // tw[4096] : e^{-2 pi i j / 8192}
#define WS_H1  12288     // H1s[8192]: DIF-FFT(conj-chirp c), pre-scaled 1/8192, bit-reversed
#define WS_H2  20480     // H2s[8192]: same for d
#define WS_QKV 28672     // float2 offset where staged q/k/v planes start (as floats)
// tables: 28672 float2 = 229376 bytes; then q/k/v planes: 3 x 1M floats = 12 MB

__device__ __forceinline__ float2 cmulf(float2 a, float2 b) {
  return make_float2(a.x * b.x - a.y * b.y, a.x * b.y + a.y * b.x);
}
__device__ __forceinline__ float2 cmulcf(float2 a, float2 b) {  // a * conj(b)
  return make_float2(a.x * b.x + a.y * b.y, a.y * b.x - a.x * b.y);
}

// DIF radix-2: natural in -> bit-reversed out, twiddle e^{-2pi i/M}.
template <int NT>
static __device__ void fft_dif(float2* buf, const float2* __restrict__ tw) {
  const int tid = threadIdx.x;
  for (int st = 0; st < 13; ++st) {
    const int h = 4096 >> st;
    __syncthreads();
    #pragma unroll
    for (int r = 0; r < 4096 / NT; ++r) {
      const int b  = tid + r * NT;
      const int j  = b & (h - 1);
      const int g  = b >> (12 - st);
      const int i0 = (g << (13 - st)) + j;
      const int i1 = i0 + h;
      const float2 u = buf[i0];
      const float2 v = buf[i1];
      const float2 s = make_float2(u.x + v.x, u.y + v.y);
      const float2 t = make_float2(u.x - v.x, u.y - v.y);
      const float2 w = tw[j << st];
      buf[i0] = s;
      buf[i1] = make_float2(t.x * w.x - t.y * w.y, t.x * w.y + t.y * w.x);
    }
  }
  __syncthreads();
}

// DIT radix-2 inverse: bit-reversed in -> natural out, twiddle e^{+2pi i/M}.
// fft_dit_inv(fft_dif(x)) = 8192 * x (scale folded into H1s/H2s).
template <int NT>
static __device__ void fft_dit_inv(float2* buf, const float2* __restrict__ tw) {
  const int tid = threadIdx.x;
  for (int st = 12; st >= 0; --st) {
    const int h = 4096 >> st;
    __syncthreads();
    #pragma unroll
    for (int r = 0; r < 4096 / NT; ++r) {
      const int b  = tid + r * NT;
      const int j  = b & (h - 1);
      const int g  = b >> (12 - st);
      const int i0 = (g << (13 - st)) + j;
      const int i1 = i0 + h;
      const float2 w = tw[j << st];
      const float2 v = buf[i1];
      const float2 t = make_float2(v.x * w.x + v.y * w.y, v.y * w.x - v.x * w.y); // v*conj(w)
      const float2 u = buf[i0];
      buf[i0] = make_float2(u.x + t.x, u.y + t.y);
      buf[i1] = make_float2(u.x - t.x, u.y - t.y);
    }
  }
  __syncthreads();
}

extern "C" __global__ void setup_tables(float2* ws) {
  const int idx = blockIdx.x * 512 + threadIdx.x;
  if (idx < 4096) {
    const long p = ((long)idx * idx) % 16382;      // j^2 mod 2*8191
    const double th = -M_PI * (double)p / 8191.0;
    double s, c; sincos(th, &s, &c);
    ws[WS_C + idx] = make_float2((float)c, (float)s);
  } else if (idx < 8192) {
    const int j = idx - 4096;
    const long p = ((long)j * j) % 16380;          // j^2 mod 2*8190
    const double th = M_PI * (double)p / 8190.0;
    double s, c; sincos(th, &s, &c);
    ws[WS_D + j] = make_float2((float)c, (float)s);
  } else if (idx < 12288) {
    const int j = idx - 8192;
    const double th = -M_PI * (double)j / 4096.0;  // e^{-2pi i j/8192}
    double s, c; sincos(th, &s, &c);
    ws[WS_TW + j] = make_float2((float)c, (float)s);
  }
}

extern "C" __global__ __launch_bounds__(512, 1) void setup_filters(float2* ws) {
  __shared__ float2 buf[M_];
  const float2* src = ws + (blockIdx.x == 0 ? WS_C : WS_D);
  float2*       dst = ws + (blockIdx.x == 0 ? WS_H1 : WS_H2);
  const float2* tw  = ws + WS_TW;
  for (int i = threadIdx.x; i < M_; i += 512) {
    float2 val = make_float2(0.f, 0.f);
    if (i != 4096) {                       // kernel support |j| <= 4095
      const int jj = (i <= 4095) ? i : (M_ - i);   // chirp is even in j
      const float2 e = src[jj];
      val = make_float2(e.x, -e.y);        // conj(chirp)
    }
    buf[i] = val;
  }
  fft_dif<512>(buf, tw);
  const float sc = 1.0f / 8192.0f;         // fold IFFT scaling into the filter
  for (int i = threadIdx.x; i < M_; i += 512)
    dst[i] = make_float2(buf[i].x * sc, buf[i].y * sc);
}

// ---------------- projection kernel: q/k/v planes [256][4096] into ws ----------------
extern "C" __global__ __launch_bounds__(256)
void proj_kernel(const float* __restrict__ queries, const float* __restrict__ keys,
                 const float* __restrict__ values,
                 const float* __restrict__ Wq, const float* __restrict__ bq,
                 const float* __restrict__ Wk, const float* __restrict__ bk,
                 const float* __restrict__ Wv, const float* __restrict__ bv,
                 float* __restrict__ q_ws, float* __restrict__ k_ws,
                 float* __restrict__ v_ws)
{
  const int tid   = threadIdx.x;
  const int wave  = tid >> 6;
  const int lane  = tid & 63;
  const int lane16 = lane & 15;
  const int hq    = lane >> 4;           // 0..3
  const int blk   = blockIdx.x;          // 2048 blocks
  const int b     = blk >> 6;            // 0..31
  const int lbase = (blk & 63) << 6;     // 0..4032 step 64

  const float* srcs[3] = {queries, keys, values};
  const float* Wsx[3]  = {Wq, Wk, Wv};
  const float* Bsx[3]  = {bq, bk, bv};
  float* dsts[3] = {q_ws, k_ws, v_ws};

  #pragma unroll
  for (int s = 0; s < 3; ++s) {
    const float* base = srcs[s] + (size_t)b * (L_ * 512);
    const float4 w4 = reinterpret_cast<const float4*>(Wsx[s])[lane16];
    const float bias = Bsx[s][0];
    float* dst = dsts[s];
    for (int i = 0; i < 16; ++i) {
      const int l = lbase + (i << 2) + wave;
      const float4* p = reinterpret_cast<const float4*>(base + (size_t)l * 512);
      const float4 x1 = p[lane];        // h = hq,   d-quad = lane16
      const float4 x2 = p[64 + lane];   // h = hq+4, d-quad = lane16
      if (s < 2) {
        double d1 = (double)x1.x * w4.x + (double)x1.y * w4.y +
                    (double)x1.z * w4.z + (double)x1.w * w4.w;
        double d2 = (double)x2.x * w4.x + (double)x2.y * w4.y +
                    (double)x2.z * w4.z + (double)x2.w * w4.w;
        d1 += __shfl_xor(d1, 1); d2 += __shfl_xor(d2, 1);
        d1 += __shfl_xor(d1, 2); d2 += __shfl_xor(d2, 2);
        d1 += __shfl_xor(d1, 4); d2 += __shfl_xor(d2, 4);
        d1 += __shfl_xor(d1, 8); d2 += __shfl_xor(d2, 8);
        if (lane16 == 0) {
          dst[((size_t)(b * 8 + hq)     << 12) + l] = (float)(d1 + (double)bias);
          dst[((size_t)(b * 8 + hq + 4) << 12) + l] = (float)(d2 + (double)bias);
        }
      } else {
        float f1 = x1.x * w4.x + x1.y * w4.y + x1.z * w4.z + x1.w * w4.w;
        float f2 = x2.x * w4.x + x2.y * w4.y + x2.z * w4.z + x2.w * w4.w;
        f1 += __shfl_xor(f1, 1); f2 += __shfl_xor(f2, 1);
        f1 += __shfl_xor(f1, 2); f2 += __shfl_xor(f2, 2);
        f1 += __shfl_xor(f1, 4); f2 += __shfl_xor(f2, 4);
        f1 += __shfl_xor(f1, 8); f2 += __shfl_xor(f2, 8);
        if (lane16 == 0) {
          dst[((size_t)(b * 8 + hq)     << 12) + l] = f1 + bias;
          dst[((size_t)(b * 8 + hq + 4) << 12) + l] = f2 + bias;
        }
      }
    }
  }
}

// ---------------- main kernel: CZT scores + topk + softmax + gather ----------------
extern "C" __global__ __launch_bounds__(1024, 1)
void autocorr_main(const float2* __restrict__ ws,
                   const float* __restrict__ q_ws, const float* __restrict__ k_ws,
                   const float* __restrict__ v_ws, float* __restrict__ outp)
{
  __shared__ float2 buf[M_];        // 64 KB FFT buffer
  __shared__ float  v_lds[L_];      // 16 KB
  __shared__ float  cand_v[16 * KK];
  __shared__ int    cand_i[16 * KK];
  __shared__ float  w_sh[KK];
  __shared__ int    i_sh[KK];

  const int tid = threadIdx.x;
  const int bh  = blockIdx.x;

  const float2* c_t = ws + WS_C;
  const float2* d_t = ws + WS_D;
  const float2* tw  = ws + WS_TW;
  const float2* H1  = ws + WS_H1;
  const float2* H2  = ws + WS_H2;
  const float* qrow = q_ws + ((size_t)bh << 12);
  const float* krow = k_ws + ((size_t)bh << 12);
  const float* vrow = v_ws + ((size_t)bh << 12);

  // v into LDS (barrier before phase D use is implied by FFT barriers)
  #pragma unroll
  for (int r = 0; r < 4; ++r) v_lds[tid + (r << 10)] = vrow[tid + (r << 10)];

  // ---------------- K forward CZT (8191-grid): K_m = c_m * IFFT(FFT(k*c) . H1)[m]
  #pragma unroll
  for (int r = 0; r < 4; ++r) {
    const int i = tid + (r << 10);
    const float kv = krow[i];
    const float2 cc = c_t[i];
    buf[i] = make_float2(kv * cc.x, kv * cc.y);
  }
  #pragma unroll
  for (int r = 4; r < 8; ++r) buf[tid + (r << 10)] = make_float2(0.f, 0.f);
  fft_dif<1024>(buf, tw);
  #pragma unroll
  for (int r = 0; r < 8; ++r) { const int i = tid + (r << 10); buf[i] = cmulf(buf[i], H1[i]); }
  fft_dit_inv<1024>(buf, tw);
  float2 Kr[4];
  #pragma unroll
  for (int r = 0; r < 4; ++r) { const int m = tid + (r << 10); Kr[r] = cmulf(c_t[m], buf[m]); }
  // per-slot reader == writer == (slot & 1023), no cross-thread hazard before rebuild

  // ---------------- Q forward CZT, then F = Q * conj(K) in registers
  #pragma unroll
  for (int r = 0; r < 4; ++r) {
    const int i = tid + (r << 10);
    const float qv = qrow[i];
    const float2 cc = c_t[i];
    buf[i] = make_float2(qv * cc.x, qv * cc.y);
  }
  #pragma unroll
  for (int r = 4; r < 8; ++r) buf[tid + (r << 10)] = make_float2(0.f, 0.f);
  fft_dif<1024>(buf, tw);
  #pragma unroll
  for (int r = 0; r < 8; ++r) { const int i = tid + (r << 10); buf[i] = cmulf(buf[i], H1[i]); }
  fft_dit_inv<1024>(buf, tw);
  float2 Fr[4];
  #pragma unroll
  for (int r = 0; r < 4; ++r) {
    const int m = tid + (r << 10);
    const float2 Q = cmulf(c_t[m], buf[m]);
    Fr[r] = cmulcf(Q, Kr[r]);
  }

  // ---------------- inverse via irfft_8190 semantics (Bluestein CZT)
  // y_t = Re( d_t * IFFT(FFT(g.d) . H2)[t] ) / 8190, g = [ReF0, 2F_1..2F_4094, ReF_4095]
  #pragma unroll
  for (int r = 0; r < 4; ++r) {
    const int m = tid + (r << 10);
    const float2 F = Fr[r];
    float2 g;
    if (m == 0 || m == 4095) g = make_float2(F.x, 0.f);   // DC/Nyquist: Im dropped
    else                     g = make_float2(2.f * F.x, 2.f * F.y);
    buf[m] = cmulf(g, d_t[m]);
  }
  #pragma unroll
  for (int r = 4; r < 8; ++r) buf[tid + (r << 10)] = make_float2(0.f, 0.f);
  fft_dif<1024>(buf, tw);
  #pragma unroll
  for (int r = 0; r < 8; ++r) { const int i = tid + (r << 10); buf[i] = cmulf(buf[i], H2[i]); }
  fft_dit_inv<1024>(buf, tw);

  // ---------------- scores + per-wave top-45 ----------------
  const float SCALE = (float)(1.0 / (8190.0 * 4096.0));   // /8190 (irfft) then /4096 (L)
  float svv[4]; int sii[4];
  #pragma unroll
  for (int r = 0; r < 4; ++r) {
    const int t = tid + (r << 10);
    const float2 Z = cmulf(d_t[t], buf[t]);
    svv[r] = Z.x * SCALE;
    sii[r] = t;
  }
  const int lane = tid & 63, wv = tid >> 6;   // 16 waves
  for (int it = 0; it < KK; ++it) {
    float bvv = -FLT_MAX; int bii = 0x7fffffff;
    #pragma unroll
    for (int c = 0; c < 4; ++c)
      if (svv[c] > bvv || (svv[c] == bvv && sii[c] < bii)) { bvv = svv[c]; bii = sii[c]; }
    #pragma unroll
    for (int off = 1; off < 64; off <<= 1) {
      const float ov = __shfl_xor(bvv, off);
      const int   oi = __shfl_xor(bii, off);
      if (ov > bvv || (ov == bvv && oi < bii)) { bvv = ov; bii = oi; }
    }
    #pragma unroll
    for (int c = 0; c < 4; ++c) if (sii[c] == bii) svv[c] = -FLT_MAX;
    if (lane == 0) { cand_v[wv * KK + it] = bvv; cand_i[wv * KK + it] = bii; }
  }
  __syncthreads();

  // ---------------- merge 16x45 + softmax (wave 0) ----------------
  if (tid < 64) {
    float mv[12]; int mi[12];
    #pragma unroll
    for (int c = 0; c < 12; ++c) {
      const int id = tid + 64 * c;
      if (id < 16 * KK) { mv[c] = cand_v[id]; mi[c] = cand_i[id]; }
      else              { mv[c] = -FLT_MAX;   mi[c] = 0x7fffffff; }
    }
    float m0 = 0.f, sum = 0.f, myv = -FLT_MAX; int myi = 0;
    for (int it = 0; it < KK; ++it) {
      float bvv = -FLT_MAX; int bii = 0x7fffffff;
      #pragma unroll
      for (int c = 0; c < 12; ++c)
        if (mv[c] > bvv || (mv[c] == bvv && mi[c] < bii)) { bvv = mv[c]; bii = mi[c]; }
      #pragma unroll
      for (int off = 1; off < 64; off <<= 1) {
        const float ov = __shfl_xor(bvv, off);
        const int   oi = __shfl_xor(bii, off);
        if (ov > bvv || (ov == bvv && oi < bii)) { bvv = ov; bii = oi; }
      }
      if (it == 0) m0 = bvv;
      sum += expf(bvv - m0);               // identical on all lanes
      if (tid == it) { myv = bvv; myi = bii; }
      #pragma unroll
      for (int c = 0; c < 12; ++c) if (mi[c] == bii) mv[c] = -FLT_MAX;
    }
    if (tid < KK) { w_sh[tid] = expf(myv - m0) / sum; i_sh[tid] = myi; }
  }
  __syncthreads();

  // ---------------- gather: out[t] = sum_j w_j * v[(idx_j + t) & 4095] ------------
  {
    float acc[4] = {0, 0, 0, 0};
    for (int j = 0; j < KK; ++j) {
      const float wj = w_sh[j];
      const int   bse = i_sh[j] + tid;
      #pragma unroll
      for (int r = 0; r < 4; ++r)
        acc[r] = fmaf(wj, v_lds[(bse + (r << 10)) & (L_ - 1)], acc[r]);
    }
    float* op = outp + ((size_t)bh << 12);
    #pragma unroll
    for (int r = 0; r < 4; ++r) op[tid + (r << 10)] = acc[r];
  }
}

extern "C" void kernel_launch(void* const* d_in, const int* in_sizes, int n_in,
                              void* d_out, int out_size, void* d_ws, size_t ws_size,
                              hipStream_t stream) {
  const float* queries = (const float*)d_in[0];
  const float* keys    = (const float*)d_in[1];
  const float* values  = (const float*)d_in[2];
  const float* Wq = (const float*)d_in[3];
  const float* bq = (const float*)d_in[4];
  const float* Wk = (const float*)d_in[5];
  const float* bk = (const float*)d_in[6];
  const float* Wv = (const float*)d_in[7];
  const float* bv = (const float*)d_in[8];
  float2* ws = (float2*)d_ws;
  float* q_ws = (float*)d_ws + 2 * WS_QKV;
  float* k_ws = q_ws + (1 << 20);
  float* v_ws = k_ws + (1 << 20);
  float* out = (float*)d_out;

  hipLaunchKernelGGL(setup_tables,  dim3(24), dim3(512), 0, stream, ws);
  hipLaunchKernelGGL(setup_filters, dim3(2),  dim3(512), 0, stream, ws);
  hipLaunchKernelGGL(proj_kernel,   dim3(2048), dim3(256), 0, stream,
                     queries, keys, values, Wq, bq, Wk, bk, Wv, bv, q_ws, k_ws, v_ws);
  hipLaunchKernelGGL(autocorr_main, dim3(256), dim3(1024), 0, stream,
                     ws, q_ws, k_ws, v_ws, out);
}

// Round 4
// 344.146 us; speedup vs baseline: 1.5033x; 1.1521x over previous
//
#include <hip/hip_runtime.h>
#include <math.h>
#include <float.h>

#define L_   4096
#define M_   8192
#define H_   8
#define D_   64
#define KK   45          // 5 * ceil(ln(4096))

// ws layout in float2 units
#define WS_C   0         // c[4096]  : e^{-i pi j^2 / 8191}
#define WS_D   4096      // d[4096]  : e^{+i pi j^2 / 8190}
#define WS_TW  8192      // tw[8192] : e^{-2 pi i j / 8192}  (radix-4 needs up to w^{3j})
#define WS_H1  16384     // H1s[8192]: DIF-FFT(conj-chirp c), pre-scaled 1/8192, digit-reversed
#define WS_H2  24576     // H2s[8192]: same for d
#define WS_QKV 32768     // float2 offset where staged q/k/v planes start
// tables: 32768 float2 = 256 KB; then q/k/v planes: 3 x 1M floats = 12 MB

__device__ __forceinline__ float2 cadd(float2 a, float2 b) { return make_float2(a.x + b.x, a.y + b.y); }
__device__ __forceinline__ float2 csub(float2 a, float2 b) { return make_float2(a.x - b.x, a.y - b.y); }
__device__ __forceinline__ float2 cmulf(float2 a, float2 b) {
  return make_float2(a.x * b.x - a.y * b.y, a.x * b.y + a.y * b.x);
}
__device__ __forceinline__ float2 cmulcf(float2 a, float2 b) {  // a * conj(b)
  return make_float2(a.x * b.x + a.y * b.y, a.y * b.x - a.x * b.y);
}

// ---------------- radix-4 DIF: natural in -> digit-reversed out ----------------
// 6 radix-4 stages + final radix-2 stage.  Twiddle e^{-2pi i/M}.
template <int NT>
static __device__ void fft_dif(float2* buf, const float2* __restrict__ tw) {
  const int tid = threadIdx.x;
  #pragma unroll
  for (int s = 0; s < 6; ++s) {
    const int q = 2048 >> (2 * s);
    __syncthreads();
    #pragma unroll
    for (int r = 0; r < 2048 / NT; ++r) {
      const int bid = tid + r * NT;
      const int j   = bid & (q - 1);
      const int i0  = ((bid >> (11 - 2 * s)) << (13 - 2 * s)) + j;
      const int e   = j << (2 * s);
      const float2 w1 = tw[e], w2 = tw[2 * e], w3 = tw[3 * e];
      const float2 a = buf[i0], b = buf[i0 + q], c = buf[i0 + 2 * q], d = buf[i0 + 3 * q];
      const float2 t0 = cadd(a, c), t1 = csub(a, c), t2 = cadd(b, d), t3 = csub(b, d);
      buf[i0]         = cadd(t0, t2);
      buf[i0 + q]     = cmulf(make_float2(t1.x + t3.y, t1.y - t3.x), w1);  // (t1 - i t3) w1
      buf[i0 + 2 * q] = cmulf(csub(t0, t2), w2);
      buf[i0 + 3 * q] = cmulf(make_float2(t1.x - t3.y, t1.y + t3.x), w3);  // (t1 + i t3) w3
    }
  }
  __syncthreads();
  #pragma unroll
  for (int r = 0; r < 4096 / NT; ++r) {
    const int i0 = (tid + r * NT) << 1;
    const float2 a = buf[i0], b = buf[i0 + 1];
    buf[i0] = cadd(a, b); buf[i0 + 1] = csub(a, b);
  }
  __syncthreads();
}

// ---------------- radix-4 DIT inverse: exact stage-mirror of fft_dif ----------------
// fft_dit_inv(fft_dif(x)) = 8192 * x (scale folded into H1s/H2s).
template <int NT>
static __device__ void fft_dit_inv(float2* buf, const float2* __restrict__ tw) {
  const int tid = threadIdx.x;
  __syncthreads();
  #pragma unroll
  for (int r = 0; r < 4096 / NT; ++r) {
    const int i0 = (tid + r * NT) << 1;
    const float2 a = buf[i0], b = buf[i0 + 1];
    buf[i0] = cadd(a, b); buf[i0 + 1] = csub(a, b);
  }
  #pragma unroll
  for (int s = 5; s >= 0; --s) {
    const int q = 2048 >> (2 * s);
    __syncthreads();
    #pragma unroll
    for (int r = 0; r < 2048 / NT; ++r) {
      const int bid = tid + r * NT;
      const int j   = bid & (q - 1);
      const int i0  = ((bid >> (11 - 2 * s)) << (13 - 2 * s)) + j;
      const int e   = j << (2 * s);
      const float2 w1 = tw[e], w2 = tw[2 * e], w3 = tw[3 * e];
      const float2 z0 = buf[i0];
      const float2 z1 = cmulcf(buf[i0 + q],     w1);
      const float2 z2 = cmulcf(buf[i0 + 2 * q], w2);
      const float2 z3 = cmulcf(buf[i0 + 3 * q], w3);
      const float2 t0 = cadd(z0, z2), t1 = csub(z0, z2), t2 = cadd(z1, z3), u = csub(z1, z3);
      buf[i0]         = cadd(t0, t2);
      buf[i0 + q]     = make_float2(t1.x - u.y, t1.y + u.x);   // t1 + i u
      buf[i0 + 2 * q] = csub(t0, t2);
      buf[i0 + 3 * q] = make_float2(t1.x + u.y, t1.y - u.x);   // t1 - i u
    }
  }
  __syncthreads();
}

// ---------------- fused dual-buffer variants (NT = 1024 hardcoded) ----------------
static __device__ void fft_dif2(float2* A, float2* B, const float2* __restrict__ tw) {
  const int tid = threadIdx.x;
  #pragma unroll
  for (int s = 0; s < 6; ++s) {
    const int q = 2048 >> (2 * s);
    __syncthreads();
    #pragma unroll
    for (int r = 0; r < 2; ++r) {
      const int bid = tid + (r << 10);
      const int j   = bid & (q - 1);
      const int i0  = ((bid >> (11 - 2 * s)) << (13 - 2 * s)) + j;
      const int e   = j << (2 * s);
      const float2 w1 = tw[e], w2 = tw[2 * e], w3 = tw[3 * e];
      {
        const float2 a = A[i0], b = A[i0 + q], c = A[i0 + 2 * q], d = A[i0 + 3 * q];
        const float2 t0 = cadd(a, c), t1 = csub(a, c), t2 = cadd(b, d), t3 = csub(b, d);
        A[i0]         = cadd(t0, t2);
        A[i0 + q]     = cmulf(make_float2(t1.x + t3.y, t1.y - t3.x), w1);
        A[i0 + 2 * q] = cmulf(csub(t0, t2), w2);
        A[i0 + 3 * q] = cmulf(make_float2(t1.x - t3.y, t1.y + t3.x), w3);
      }
      {
        const float2 a = B[i0], b = B[i0 + q], c = B[i0 + 2 * q], d = B[i0 + 3 * q];
        const float2 t0 = cadd(a, c), t1 = csub(a, c), t2 = cadd(b, d), t3 = csub(b, d);
        B[i0]         = cadd(t0, t2);
        B[i0 + q]     = cmulf(make_float2(t1.x + t3.y, t1.y - t3.x), w1);
        B[i0 + 2 * q] = cmulf(csub(t0, t2), w2);
        B[i0 + 3 * q] = cmulf(make_float2(t1.x - t3.y, t1.y + t3.x), w3);
      }
    }
  }
  __syncthreads();
  #pragma unroll
  for (int r = 0; r < 4; ++r) {
    const int i0 = (tid + (r << 10)) << 1;
    { const float2 a = A[i0], b = A[i0 + 1]; A[i0] = cadd(a, b); A[i0 + 1] = csub(a, b); }
    { const float2 a = B[i0], b = B[i0 + 1]; B[i0] = cadd(a, b); B[i0 + 1] = csub(a, b); }
  }
  __syncthreads();
}

static __device__ void fft_dit_inv2(float2* A, float2* B, const float2* __restrict__ tw) {
  const int tid = threadIdx.x;
  __syncthreads();
  #pragma unroll
  for (int r = 0; r < 4; ++r) {
    const int i0 = (tid + (r << 10)) << 1;
    { const float2 a = A[i0], b = A[i0 + 1]; A[i0] = cadd(a, b); A[i0 + 1] = csub(a, b); }
    { const float2 a = B[i0], b = B[i0 + 1]; B[i0] = cadd(a, b); B[i0 + 1] = csub(a, b); }
  }
  #pragma unroll
  for (int s = 5; s >= 0; --s) {
    const int q = 2048 >> (2 * s);
    __syncthreads();
    #pragma unroll
    for (int r = 0; r < 2; ++r) {
      const int bid = tid + (r << 10);
      const int j   = bid & (q - 1);
      const int i0  = ((bid >> (11 - 2 * s)) << (13 - 2 * s)) + j;
      const int e   = j << (2 * s);
      const float2 w1 = tw[e], w2 = tw[2 * e], w3 = tw[3 * e];
      {
        const float2 z0 = A[i0];
        const float2 z1 = cmulcf(A[i0 + q], w1);
        const float2 z2 = cmulcf(A[i0 + 2 * q], w2);
        const float2 z3 = cmulcf(A[i0 + 3 * q], w3);
        const float2 t0 = cadd(z0, z2), t1 = csub(z0, z2), t2 = cadd(z1, z3), u = csub(z1, z3);
        A[i0]         = cadd(t0, t2);
        A[i0 + q]     = make_float2(t1.x - u.y, t1.y + u.x);
        A[i0 + 2 * q] = csub(t0, t2);
        A[i0 + 3 * q] = make_float2(t1.x + u.y, t1.y - u.x);
      }
      {
        const float2 z0 = B[i0];
        const float2 z1 = cmulcf(B[i0 + q], w1);
        const float2 z2 = cmulcf(B[i0 + 2 * q], w2);
        const float2 z3 = cmulcf(B[i0 + 3 * q], w3);
        const float2 t0 = cadd(z0, z2), t1 = csub(z0, z2), t2 = cadd(z1, z3), u = csub(z1, z3);
        B[i0]         = cadd(t0, t2);
        B[i0 + q]     = make_float2(t1.x - u.y, t1.y + u.x);
        B[i0 + 2 * q] = csub(t0, t2);
        B[i0 + 3 * q] = make_float2(t1.x + u.y, t1.y - u.x);
      }
    }
  }
  __syncthreads();
}

extern "C" __global__ void setup_tables(float2* ws) {
  const int idx = blockIdx.x * 512 + threadIdx.x;
  if (idx < 4096) {
    const long p = ((long)idx * idx) % 16382;      // j^2 mod 2*8191
    const double th = -M_PI * (double)p / 8191.0;
    double s, c; sincos(th, &s, &c);
    ws[WS_C + idx] = make_float2((float)c, (float)s);
  } else if (idx < 8192) {
    const int j = idx - 4096;
    const long p = ((long)j * j) % 16380;          // j^2 mod 2*8190
    const double th = M_PI * (double)p / 8190.0;
    double s, c; sincos(th, &s, &c);
    ws[WS_D + j] = make_float2((float)c, (float)s);
  } else if (idx < 16384) {
    const int j = idx - 8192;
    const double th = -M_PI * (double)j / 4096.0;  // e^{-2pi i j/8192}, j < 8192
    double s, c; sincos(th, &s, &c);
    ws[WS_TW + j] = make_float2((float)c, (float)s);
  }
}

extern "C" __global__ __launch_bounds__(512, 1) void setup_filters(float2* ws) {
  __shared__ float2 buf[M_];
  const float2* src = ws + (blockIdx.x == 0 ? WS_C : WS_D);
  float2*       dst = ws + (blockIdx.x == 0 ? WS_H1 : WS_H2);
  const float2* tw  = ws + WS_TW;
  for (int i = threadIdx.x; i < M_; i += 512) {
    float2 val = make_float2(0.f, 0.f);
    if (i != 4096) {                       // kernel support |j| <= 4095
      const int jj = (i <= 4095) ? i : (M_ - i);   // chirp is even in j
      const float2 e = src[jj];
      val = make_float2(e.x, -e.y);        // conj(chirp)
    }
    buf[i] = val;
  }
  fft_dif<512>(buf, tw);
  const float sc = 1.0f / 8192.0f;         // fold IFFT scaling into the filter
  for (int i = threadIdx.x; i < M_; i += 512)
    dst[i] = make_float2(buf[i].x * sc, buf[i].y * sc);
}

// ---------------- projection kernel: q/k/v planes [256][4096] into ws ----------------
extern "C" __global__ __launch_bounds__(256)
void proj_kernel(const float* __restrict__ queries, const float* __restrict__ keys,
                 const float* __restrict__ values,
                 const float* __restrict__ Wq, const float* __restrict__ bq,
                 const float* __restrict__ Wk, const float* __restrict__ bk,
                 const float* __restrict__ Wv, const float* __restrict__ bv,
                 float* __restrict__ q_ws, float* __restrict__ k_ws,
                 float* __restrict__ v_ws)
{
  const int tid   = threadIdx.x;
  const int wave  = tid >> 6;
  const int lane  = tid & 63;
  const int lane16 = lane & 15;
  const int hq    = lane >> 4;           // 0..3
  const int blk   = blockIdx.x;          // 2048 blocks
  const int b     = blk >> 6;            // 0..31
  const int lbase = (blk & 63) << 6;     // 0..4032 step 64

  const float* srcs[3] = {queries, keys, values};
  const float* Wsx[3]  = {Wq, Wk, Wv};
  const float* Bsx[3]  = {bq, bk, bv};
  float* dsts[3] = {q_ws, k_ws, v_ws};

  #pragma unroll
  for (int s = 0; s < 3; ++s) {
    const float* base = srcs[s] + (size_t)b * (L_ * 512);
    const float4 w4 = reinterpret_cast<const float4*>(Wsx[s])[lane16];
    const float bias = Bsx[s][0];
    float* dst = dsts[s];
    for (int ii = 0; ii < 4; ++ii) {
      float4 xa[4], xb[4];
      #pragma unroll
      for (int u = 0; u < 4; ++u) {          // 8 independent loads in flight
        const int l = lbase + (((ii << 2) + u) << 2) + wave;
        const float4* p = reinterpret_cast<const float4*>(base + (size_t)l * 512);
        xa[u] = p[lane];                     // h = hq,   d-quad = lane16
        xb[u] = p[64 + lane];                // h = hq+4, d-quad = lane16
      }
      #pragma unroll
      for (int u = 0; u < 4; ++u) {
        const int l = lbase + (((ii << 2) + u) << 2) + wave;
        if (s < 2) {
          double d1 = (double)xa[u].x * w4.x + (double)xa[u].y * w4.y +
                      (double)xa[u].z * w4.z + (double)xa[u].w * w4.w;
          double d2 = (double)xb[u].x * w4.x + (double)xb[u].y * w4.y +
                      (double)xb[u].z * w4.z + (double)xb[u].w * w4.w;
          d1 += __shfl_xor(d1, 1); d2 += __shfl_xor(d2, 1);
          d1 += __shfl_xor(d1, 2); d2 += __shfl_xor(d2, 2);
          d1 += __shfl_xor(d1, 4); d2 += __shfl_xor(d2, 4);
          d1 += __shfl_xor(d1, 8); d2 += __shfl_xor(d2, 8);
          if (lane16 == 0) {
            dst[((size_t)(b * 8 + hq)     << 12) + l] = (float)(d1 + (double)bias);
            dst[((size_t)(b * 8 + hq + 4) << 12) + l] = (float)(d2 + (double)bias);
          }
        } else {
          float f1 = xa[u].x * w4.x + xa[u].y * w4.y + xa[u].z * w4.z + xa[u].w * w4.w;
          float f2 = xb[u].x * w4.x + xb[u].y * w4.y + xb[u].z * w4.z + xb[u].w * w4.w;
          f1 += __shfl_xor(f1, 1); f2 += __shfl_xor(f2, 1);
          f1 += __shfl_xor(f1, 2); f2 += __shfl_xor(f2, 2);
          f1 += __shfl_xor(f1, 4); f2 += __shfl_xor(f2, 4);
          f1 += __shfl_xor(f1, 8); f2 += __shfl_xor(f2, 8);
          if (lane16 == 0) {
            dst[((size_t)(b * 8 + hq)     << 12) + l] = f1 + bias;
            dst[((size_t)(b * 8 + hq + 4) << 12) + l] = f2 + bias;
          }
        }
      }
    }
  }
}

// ---------------- main kernel: CZT scores + topk + softmax + gather ----------------
extern "C" __global__ __launch_bounds__(1024, 1)
void autocorr_main(const float2* __restrict__ ws,
                   const float* __restrict__ q_ws, const float* __restrict__ k_ws,
                   const float* __restrict__ v_ws, float* __restrict__ outp)
{
  __shared__ float2 bufA[M_];       // 64 KB (K path, then inverse-CZT)
  __shared__ float2 bufB[M_];       // 64 KB (Q path)
  __shared__ float  v_lds[L_];      // 16 KB
  __shared__ float  cand_v[16 * KK];
  __shared__ int    cand_i[16 * KK];
  __shared__ float  w_sh[KK];
  __shared__ int    i_sh[KK];

  const int tid = threadIdx.x;
  const int bh  = blockIdx.x;

  const float2* c_t = ws + WS_C;
  const float2* d_t = ws + WS_D;
  const float2* tw  = ws + WS_TW;
  const float2* H1  = ws + WS_H1;
  const float2* H2  = ws + WS_H2;
  const float* qrow = q_ws + ((size_t)bh << 12);
  const float* krow = k_ws + ((size_t)bh << 12);
  const float* vrow = v_ws + ((size_t)bh << 12);

  // load v, and chirp-premultiplied k (bufA) / q (bufB); zero-pad 4096..8191
  #pragma unroll
  for (int r = 0; r < 4; ++r) {
    const int i = tid + (r << 10);
    v_lds[i] = vrow[i];
    const float2 cc = c_t[i];
    const float kv = krow[i];
    const float qv = qrow[i];
    bufA[i] = make_float2(kv * cc.x, kv * cc.y);
    bufB[i] = make_float2(qv * cc.x, qv * cc.y);
  }
  #pragma unroll
  for (int r = 4; r < 8; ++r) {
    const int i = tid + (r << 10);
    bufA[i] = make_float2(0.f, 0.f);
    bufB[i] = make_float2(0.f, 0.f);
  }

  // ------- fused forward CZT for K (A) and Q (B): IFFT(FFT(x*c) . H1) -------
  fft_dif2(bufA, bufB, tw);
  #pragma unroll
  for (int r = 0; r < 8; ++r) {
    const int i = tid + (r << 10);
    bufA[i] = cmulf(bufA[i], H1[i]);
    bufB[i] = cmulf(bufB[i], H1[i]);
  }
  fft_dit_inv2(bufA, bufB, tw);

  // ------- F = (c.Q) * conj(c.K); build g.d into bufA (inverse-CZT input) -------
  #pragma unroll
  for (int r = 0; r < 4; ++r) {
    const int m = tid + (r << 10);
    const float2 cc = c_t[m];
    const float2 K = cmulf(cc, bufA[m]);
    const float2 Q = cmulf(cc, bufB[m]);
    const float2 F = cmulcf(Q, K);
    float2 g;
    if (m == 0 || m == 4095) g = make_float2(F.x, 0.f);   // DC/Nyquist: Im dropped
    else                     g = make_float2(2.f * F.x, 2.f * F.y);
    bufA[m] = cmulf(g, d_t[m]);
  }
  #pragma unroll
  for (int r = 4; r < 8; ++r) bufA[tid + (r << 10)] = make_float2(0.f, 0.f);

  // ------- inverse via irfft_8190 semantics: y_t = Re(d_t * IFFT(FFT(g.d) . H2)[t]) -------
  fft_dif<1024>(bufA, tw);
  #pragma unroll
  for (int r = 0; r < 8; ++r) {
    const int i = tid + (r << 10);
    bufA[i] = cmulf(bufA[i], H2[i]);
  }
  fft_dit_inv<1024>(bufA, tw);

  // ---------------- scores + per-wave top-45 ----------------
  const float SCALE = (float)(1.0 / (8190.0 * 4096.0));   // /8190 (irfft) then /4096 (L)
  float svv[4]; int sii[4];
  #pragma unroll
  for (int r = 0; r < 4; ++r) {
    const int t = tid + (r << 10);
    const float2 Z = cmulf(d_t[t], bufA[t]);
    svv[r] = Z.x * SCALE;
    sii[r] = t;
  }
  const int lane = tid & 63, wv = tid >> 6;   // 16 waves
  for (int it = 0; it < KK; ++it) {
    float bvv = -FLT_MAX; int bii = 0x7fffffff;
    #pragma unroll
    for (int c = 0; c < 4; ++c)
      if (svv[c] > bvv || (svv[c] == bvv && sii[c] < bii)) { bvv = svv[c]; bii = sii[c]; }
    #pragma unroll
    for (int off = 1; off < 64; off <<= 1) {
      const float ov = __shfl_xor(bvv, off);
      const int   oi = __shfl_xor(bii, off);
      if (ov > bvv || (ov == bvv && oi < bii)) { bvv = ov; bii = oi; }
    }
    #pragma unroll
    for (int c = 0; c < 4; ++c) if (sii[c] == bii) svv[c] = -FLT_MAX;
    if (lane == 0) { cand_v[wv * KK + it] = bvv; cand_i[wv * KK + it] = bii; }
  }
  __syncthreads();

  // ---------------- merge 16x45 + softmax (wave 0) ----------------
  if (tid < 64) {
    float mv[12]; int mi[12];
    #pragma unroll
    for (int c = 0; c < 12; ++c) {
      const int id = tid + 64 * c;
      if (id < 16 * KK) { mv[c] = cand_v[id]; mi[c] = cand_i[id]; }
      else              { mv[c] = -FLT_MAX;   mi[c] = 0x7fffffff; }
    }
    float m0 = 0.f, sum = 0.f, myv = -FLT_MAX; int myi = 0;
    for (int it = 0; it < KK; ++it) {
      float bvv = -FLT_MAX; int bii = 0x7fffffff;
      #pragma unroll
      for (int c = 0; c < 12; ++c)
        if (mv[c] > bvv || (mv[c] == bvv && mi[c] < bii)) { bvv = mv[c]; bii = mi[c]; }
      #pragma unroll
      for (int off = 1; off < 64; off <<= 1) {
        const float ov = __shfl_xor(bvv, off);
        const int   oi = __shfl_xor(bii, off);
        if (ov > bvv || (ov == bvv && oi < bii)) { bvv = ov; bii = oi; }
      }
      if (it == 0) m0 = bvv;
      sum += expf(bvv - m0);               // identical on all lanes
      if (tid == it) { myv = bvv; myi = bii; }
      #pragma unroll
      for (int c = 0; c < 12; ++c) if (mi[c] == bii) mv[c] = -FLT_MAX;
    }
    if (tid < KK) { w_sh[tid] = expf(myv - m0) / sum; i_sh[tid] = myi; }
  }
  __syncthreads();

  // ---------------- gather: out[t] = sum_j w_j * v[(idx_j + t) & 4095] ------------
  {
    float acc[4] = {0, 0, 0, 0};
    for (int j = 0; j < KK; ++j) {
      const float wj = w_sh[j];
      const int   bse = i_sh[j] + tid;
      #pragma unroll
      for (int r = 0; r < 4; ++r)
        acc[r] = fmaf(wj, v_lds[(bse + (r << 10)) & (L_ - 1)], acc[r]);
    }
    float* op = outp + ((size_t)bh << 12);
    #pragma unroll
    for (int r = 0; r < 4; ++r) op[tid + (r << 10)] = acc[r];
  }
}

extern "C" void kernel_launch(void* const* d_in, const int* in_sizes, int n_in,
                              void* d_out, int out_size, void* d_ws, size_t ws_size,
                              hipStream_t stream) {
  const float* queries = (const float*)d_in[0];
  const float* keys    = (const float*)d_in[1];
  const float* values  = (const float*)d_in[2];
  const float* Wq = (const float*)d_in[3];
  const float* bq = (const float*)d_in[4];
  const float* Wk = (const float*)d_in[5];
  const float* bk = (const float*)d_in[6];
  const float* Wv = (const float*)d_in[7];
  const float* bv = (const float*)d_in[8];
  float2* ws = (float2*)d_ws;
  float* q_ws = (float*)d_ws + 2 * WS_QKV;
  float* k_ws = q_ws + (1 << 20);
  float* v_ws = k_ws + (1 << 20);
  float* out = (float*)d_out;

  hipLaunchKernelGGL(setup_tables,  dim3(32), dim3(512), 0, stream, ws);
  hipLaunchKernelGGL(setup_filters, dim3(2),  dim3(512), 0, stream, ws);
  hipLaunchKernelGGL(proj_kernel,   dim3(2048), dim3(256), 0, stream,
                     queries, keys, values, Wq, bq, Wk, bk, Wv, bv, q_ws, k_ws, v_ws);
  hipLaunchKernelGGL(autocorr_main, dim3(256), dim3(1024), 0, stream,
                     ws, q_ws, k_ws, v_ws, out);
}